// Round 4
// baseline (575.804 us; speedup 1.0000x reference)
//
#include <hip/hip_runtime.h>
#include <hip/hip_bf16.h>

// Problem constants (from reference setup_inputs)
constexpr int NN   = 50000;   // nodes
constexpr int EE   = 400000;  // edges (before self loops)
constexpr int EP   = 450000;  // edges + self loops
constexpr int D    = 512;     // HEADS*CH
constexpr int D2   = 1024;    // XL||XR fused row stride
constexpr int F0   = 55;      // input feature dim
constexpr int F0P  = 64;      // padded to MFMA K granularity
constexpr int OUTC = 49;      // classifier out dim

typedef __hip_bfloat16 bf16;

using frag_ab  = __attribute__((ext_vector_type(8))) short;   // 8 bf16 (4 VGPRs)
using frag_cd4 = __attribute__((ext_vector_type(4))) float;   // 4 fp32 (16x16 acc)
typedef float v2f __attribute__((ext_vector_type(2)));        // -> v_pk_*_f32

__device__ inline void stf(float* p, float v) { *p = v; }
__device__ inline void stf(bf16* p, float v)  { *p = __float2bfloat16(v); }

// unpack 8 bf16 (packed in a uint4) to 4 float-pairs (VOP3P operands)
__device__ inline void unpack8v(uint4 u, v2f* f) {
    unsigned w[4] = {u.x, u.y, u.z, u.w};
    #pragma unroll
    for (int j = 0; j < 4; ++j) {
        __hip_bfloat162 h = *(__hip_bfloat162*)&w[j];
        float2 t = __bfloat1622float2(h);
        f[j] = v2f{t.x, t.y};
    }
}

// ---------------------------------------------------------------------------
// Round-13 GEMM (kept verbatim — measured improvement r3, now below the edge
// kernel in the profile). Deep-pipeline, 2-blocks/CU. C[M,*] = A @ Bt^T.
//   BK=32, 3-slot ring (A 16K + B 8K)x3 = 72 KB  -> 2 blocks/CU,
//   __launch_bounds__(512,4) caps VGPR at 128 to guarantee residency.
//   Per K-step/wave: stage(s+2) 3x global_load_lds, 8x ds_read_b128,
//   16x mfma_16x16x32_bf16 (setprio-wrapped), ONE barrier, counted
//   s_waitcnt vmcnt(3). T2 swizzle both-sides (rule #21): 4 chunks/row,
//   chunk ^= (row>>1)&3 (residual 2-way conflict is free, m136).
// ---------------------------------------------------------------------------
template <typename TC, int NS>
__global__ __launch_bounds__(512, 4) void gemm_dp(
    const bf16* __restrict__ A,   // [M,K]
    const bf16* __restrict__ Bt,  // [>=gridx*128 rows, K]
    TC* __restrict__ C,           // [M, Ncs]
    const float* __restrict__ bias,
    int M, int Ncs)
{
    constexpr int K  = NS * 32;
    constexpr int BM = 256, BN = 128, BK = 32;
    __shared__ __align__(16) bf16 As[3][BM * BK];   // 16 KB / slot
    __shared__ __align__(16) bf16 Bs[3][BN * BK];   //  8 KB / slot

    int bx = blockIdx.x, by = blockIdx.y;
    if (gridDim.x == 8) {
        int bid = by * 8 + bx;
        bx = (bid >> 3) & 7;
        by = (bid & 7) + ((bid >> 6) << 3);
    }
    if (by * BM >= M) return;   // uniform across block

    const int tid = threadIdx.x;
    const int w   = tid >> 6;       // wave 0..7
    const int l   = tid & 63;
    const int rowBase = by * BM;
    const int colBase = bx * BN;

    // ---- staging source pointers (inverse-swizzled global chunks) ----
    const bf16* gA[2];
    #pragma unroll
    for (int j = 0; j < 2; ++j) {
        int f = j * 512 + tid;
        int row = f >> 2, c = (f & 3) ^ ((row >> 1) & 3);
        int ar = rowBase + row; if (ar >= M) ar = M - 1;  // clamp, never stored
        gA[j] = A + (size_t)ar * K + c * 8;
    }
    const bf16* gB;
    {
        int f = tid;
        int row = f >> 2, c = (f & 3) ^ ((row >> 1) & 3);
        gB = Bt + (size_t)(colBase + row) * K + c * 8;    // Bt rows padded
    }

    // ---- fragment read offsets (swizzled), element units ----
    const int l15 = l & 15, l4 = l >> 4;    // l4 = k-chunk 0..3
    const int wm = (w >> 1) * 64;   // wave M-block (4 x 64 rows)
    const int wn = (w & 1) * 64;    // wave N-block (2 x 64 cols)
    int aoff[4], boff[4];
    #pragma unroll
    for (int i = 0; i < 4; ++i) {
        int ra = wm + i * 16 + l15;
        int rb = wn + i * 16 + l15;
        aoff[i] = ra * BK + ((l4 ^ ((ra >> 1) & 3)) * 8);
        boff[i] = rb * BK + ((l4 ^ ((rb >> 1) & 3)) * 8);
    }

    frag_cd4 acc[4][4] = {};

    auto stage = [&](int s) {
        int slot = s % 3;
        __builtin_amdgcn_global_load_lds(
            (const __attribute__((address_space(1))) void*)(gA[0] + s * BK),
            (__attribute__((address_space(3))) void*)(&As[slot][(w * 64) * 8]),
            16, 0, 0);
        __builtin_amdgcn_global_load_lds(
            (const __attribute__((address_space(1))) void*)(gA[1] + s * BK),
            (__attribute__((address_space(3))) void*)(&As[slot][(512 + w * 64) * 8]),
            16, 0, 0);
        __builtin_amdgcn_global_load_lds(
            (const __attribute__((address_space(1))) void*)(gB + s * BK),
            (__attribute__((address_space(3))) void*)(&Bs[slot][(w * 64) * 8]),
            16, 0, 0);
    };

    stage(0);
    if (NS > 1) stage(1);

    #pragma unroll
    for (int s = 0; s < NS; ++s) {
        if (s + 1 < NS) asm volatile("s_waitcnt vmcnt(3)" ::: "memory");
        else            asm volatile("s_waitcnt vmcnt(0)" ::: "memory");
        __builtin_amdgcn_s_barrier();
        asm volatile("" ::: "memory");

        if (s + 2 < NS) stage(s + 2);   // overwrites slot(s-1): WAR-safe

        const bf16* Ab = As[s % 3];
        const bf16* Bb = Bs[s % 3];
        frag_ab a[4], b[4];
        #pragma unroll
        for (int i = 0; i < 4; ++i) a[i] = *(const frag_ab*)&Ab[aoff[i]];
        #pragma unroll
        for (int n = 0; n < 4; ++n) b[n] = *(const frag_ab*)&Bb[boff[n]];

        __builtin_amdgcn_s_setprio(1);
        #pragma unroll
        for (int i = 0; i < 4; ++i)
            #pragma unroll
            for (int n = 0; n < 4; ++n)
                acc[i][n] = __builtin_amdgcn_mfma_f32_16x16x32_bf16(
                    a[i], b[n], acc[i][n], 0, 0, 0);
        __builtin_amdgcn_s_setprio(0);
    }

    // ---- epilogue: 16x16 C/D layout col=lane&15, row=(lane>>4)*4+reg ----
    #pragma unroll
    for (int mi = 0; mi < 4; ++mi) {
        #pragma unroll
        for (int r = 0; r < 4; ++r) {
            int row = rowBase + wm + mi * 16 + l4 * 4 + r;
            if (row >= M) continue;
            #pragma unroll
            for (int ni = 0; ni < 4; ++ni) {
                int col = colBase + wn + ni * 16 + l15;
                if (col >= Ncs) continue;
                float v = acc[mi][ni][r];
                if (bias) v += bias[col];
                stf(&C[(size_t)row * Ncs + col], v);
            }
        }
    }
}

// ---------------------------------------------------------------------------
// weight prep kernels
// ---------------------------------------------------------------------------
// fp32 W[512,512] x2 -> bf16 Wt[1024,512] (transposed, stacked), grid.z=2
__global__ void convert_transpose2(const float* __restrict__ W0,
                                   const float* __restrict__ W1,
                                   bf16* __restrict__ Wt) {
    __shared__ float tile[32][33];
    const float* W = blockIdx.z ? W1 : W0;
    bf16* dst = Wt + (size_t)blockIdx.z * D * D;
    int bn = blockIdx.x * 32, bk = blockIdx.y * 32;
    int tx = threadIdx.x & 31, ty = threadIdx.x >> 5;  // 32x8
    #pragma unroll
    for (int i = 0; i < 32; i += 8)
        tile[ty + i][tx] = W[(size_t)(bk + ty + i) * D + bn + tx];
    __syncthreads();
    #pragma unroll
    for (int i = 0; i < 32; i += 8)
        dst[(size_t)(bn + ty + i) * D + bk + tx] = __float2bfloat16(tile[tx][ty + i]);
}

__global__ void pad_convert_x(const float* __restrict__ x, bf16* __restrict__ Xp) {
    int idx = blockIdx.x * blockDim.x + threadIdx.x;
    if (idx >= NN * F0P) return;
    int n = idx >> 6, t = idx & 63;
    float v = (t < F0) ? x[n * F0 + t] : 0.f;
    Xp[idx] = __float2bfloat16(v);
}

// W1{l,r}[55,512] fp32 -> W1T[1024,64] bf16 (zero pad K), grid.y=2
__global__ void conv_transpose_w1(const float* __restrict__ Wl,
                                  const float* __restrict__ Wr,
                                  bf16* __restrict__ Wt) {
    const float* W = blockIdx.y ? Wr : Wl;
    bf16* dst = Wt + (size_t)blockIdx.y * D * F0P;
    int n = blockIdx.x;           // 512
    int k = threadIdx.x;          // 64
    float v = (k < F0) ? W[(size_t)k * D + n] : 0.f;
    dst[n * F0P + k] = __float2bfloat16(v);
}

__global__ void conv_transpose_wc(const float* __restrict__ W, bf16* __restrict__ Wt) {
    int n = blockIdx.x;           // 128
    for (int k = threadIdx.x; k < D; k += blockDim.x) {
        float v = (n < OUTC) ? W[(size_t)k * OUTC + n] : 0.f;
        Wt[(size_t)n * D + k] = __float2bfloat16(v);
    }
}

// ---------------------------------------------------------------------------
__global__ void zero_ints(int* __restrict__ p, int n) {
    int i = blockIdx.x * blockDim.x + threadIdx.x;
    if (i < n) p[i] = 0;
}

// ---------------------------------------------------------------------------
// CSR build by destination; srcPos[pos] = source node of CSR slot pos
// ---------------------------------------------------------------------------
__global__ void count_dst(const int* __restrict__ dstIdx, int* __restrict__ cnt) {
    int e = blockIdx.x * blockDim.x + threadIdx.x;
    if (e >= EP) return;
    int dst = (e < EE) ? dstIdx[e] : (e - EE);
    atomicAdd(&cnt[dst], 1);
}

__global__ void scan_blocks(const int* __restrict__ cnt, int* __restrict__ off,
                            int* __restrict__ bsum) {
    __shared__ int sh[1024];
    int i = blockIdx.x * 1024 + threadIdx.x;
    int v = (i < NN) ? cnt[i] : 0;
    sh[threadIdx.x] = v;
    __syncthreads();
    #pragma unroll
    for (int d = 1; d < 1024; d <<= 1) {
        int t = (threadIdx.x >= d) ? sh[threadIdx.x - d] : 0;
        __syncthreads();
        sh[threadIdx.x] += t;
        __syncthreads();
    }
    if (i < NN) off[i] = sh[threadIdx.x] - v;   // local exclusive
    if (threadIdx.x == 1023) bsum[blockIdx.x] = sh[1023];
}

__global__ void scan_bsums(int* __restrict__ bsum, int* __restrict__ bbase,
                           int* __restrict__ off, int nb) {
    int lane = threadIdx.x;  // single wave of 64
    int orig = (lane < nb) ? bsum[lane] : 0;
    int v = orig;
    #pragma unroll
    for (int d = 1; d < 64; d <<= 1) {
        int t = __shfl_up(v, d);
        if (lane >= d) v += t;
    }
    if (lane < nb) bbase[lane] = v - orig;      // exclusive base per block
    if (lane == 63) off[NN] = v;                // grand total
}

__global__ void add_base(int* __restrict__ off, const int* __restrict__ bbase) {
    int i = blockIdx.x * 1024 + threadIdx.x;
    if (blockIdx.x == 0 || i >= NN) return;
    off[i] += bbase[blockIdx.x];
}

__global__ void fill_srcpos(const int* __restrict__ srcIdx, const int* __restrict__ dstIdx,
                            const int* __restrict__ off, int* __restrict__ cnt,
                            int* __restrict__ srcPos) {
    int e = blockIdx.x * blockDim.x + threadIdx.x;
    if (e >= EP) return;
    int dst = (e < EE) ? dstIdx[e] : (e - EE);
    int src = (e < EE) ? srcIdx[e] : (e - EE);
    int pos = off[dst] + atomicAdd(&cnt[dst], 1);
    srcPos[pos] = src;
}

// ---------------------------------------------------------------------------
// FUSED per-node GATv2 edge phase — round-14: packed-f32 (VOP3P) inner loop.
// r3 counters: VALUBusy 77%, HBM 46% (295 MB / 80 µs), MfmaUtil 0, conflicts
// 0 -> VALU-ISSUE-bound with ~30 µs/dispatch headroom to the HBM floor.
// gfx950 has v_pk_{add,mul,fma}_f32 (double-rate packed f32); LLVM selects
// them for <2 x float> ext-vector math. Core inst count/edge-lane: 48 -> 32
// (add 8->4, mul 8->4, dot-fma 8->4, acc-fma 8->4; max stays scalar — no
// pk_max on CDNA; unpack stays 8). The shfl reduce stays on the DS pipe
// (moving it to DPP would ADD VALU work — wrong direction when VALU-bound).
// Dot order note: s2 accumulates even/odd channel pairs then cross-adds —
// benign reduction-order change; den/acc order unchanged.
// ONE wave per destination node, depth-2 prefetch, clamped-exp softmax.
// Lane l owns channels [l*8, l*8+8); head = l>>4.
// XLR row layout: [XL(512) | XR(512)] bf16, stride D2. Output Hb + bias + ELU.
// ---------------------------------------------------------------------------
__global__ __launch_bounds__(256) void gat_edge_fused(
    const bf16* __restrict__ XLR, const float* __restrict__ att,
    const int* __restrict__ off, const int* __restrict__ srcPos,
    const float* __restrict__ bias, bf16* __restrict__ Hout)
{
    int v = blockIdx.x * 4 + (threadIdx.x >> 6);
    if (v >= NN) return;
    int lane = threadIdx.x & 63;

    uint4 ru = *(const uint4*)(XLR + (size_t)v * D2 + D + lane * 8);
    v2f xr[4]; unpack8v(ru, xr);
    const float4* a4 = (const float4*)(att + lane * 8);
    float4 aa = a4[0], ab = a4[1];
    v2f at[4] = {v2f{aa.x, aa.y}, v2f{aa.z, aa.w},
                 v2f{ab.x, ab.y}, v2f{ab.z, ab.w}};
    const v2f k02 = {0.2f, 0.2f};

    int s0 = off[v], s1 = off[v + 1];
    float den = 0.f;
    v2f acc[4] = {v2f{0.f, 0.f}, v2f{0.f, 0.f}, v2f{0.f, 0.f}, v2f{0.f, 0.f}};

    uint4 lb0 = {0, 0, 0, 0}, lb1 = {0, 0, 0, 0};
    if (s0 < s1)     lb0 = *(const uint4*)(XLR + (size_t)srcPos[s0] * D2 + lane * 8);
    if (s0 + 1 < s1) lb1 = *(const uint4*)(XLR + (size_t)srcPos[s0 + 1] * D2 + lane * 8);

    for (int i = s0; i < s1; ++i) {
        uint4 cur = lb0;
        lb0 = lb1;
        if (i + 2 < s1)
            lb1 = *(const uint4*)(XLR + (size_t)srcPos[i + 2] * D2 + lane * 8);

        v2f xl[4]; unpack8v(cur, xl);
        v2f s2 = {0.f, 0.f};
        #pragma unroll
        for (int j = 0; j < 4; ++j) {
            v2f t = xl[j] + xr[j];        // v_pk_add_f32
            v2f u = t * k02;              // v_pk_mul_f32
            t.x = fmaxf(t.x, u.x);        // leaky relu (valid both signs)
            t.y = fmaxf(t.y, u.y);
            s2 = t * at[j] + s2;          // v_pk_fma_f32 (contract)
        }
        float s = s2.x + s2.y;
        s += __shfl_xor(s, 1);
        s += __shfl_xor(s, 2);
        s += __shfl_xor(s, 4);
        s += __shfl_xor(s, 8);               // 16 lanes of head hold logit
        s = fminf(fmaxf(s, -60.f), 60.f);    // shift-free softmax, clamped
        float p = __expf(s);
        den += p;
        v2f pv = {p, p};
        #pragma unroll
        for (int j = 0; j < 4; ++j) acc[j] = xl[j] * pv + acc[j];  // v_pk_fma_f32
    }
    float r = 1.f / den;
    v2f rv = {r, r};

    const float4* b4 = (const float4*)(bias + lane * 8);
    float4 ba = b4[0], bb = b4[1];
    v2f bi[4] = {v2f{ba.x, ba.y}, v2f{ba.z, ba.w},
                 v2f{bb.x, bb.y}, v2f{bb.z, bb.w}};
    uint4 ou;
    unsigned* ow = (unsigned*)&ou;
    #pragma unroll
    for (int j = 0; j < 4; ++j) {
        v2f o = acc[j] * rv + bi[j];                 // v_pk_fma_f32
        float o0 = o.x > 0.f ? o.x : (__expf(o.x) - 1.f);   // ELU
        float o1 = o.y > 0.f ? o.y : (__expf(o.y) - 1.f);
        __hip_bfloat162 h{__float2bfloat16(o0), __float2bfloat16(o1)};
        ow[j] = *(unsigned*)&h;
    }
    *(uint4*)(Hout + (size_t)v * D + lane * 8) = ou;
}

// ---------------------------------------------------------------------------
extern "C" void kernel_launch(void* const* d_in, const int* in_sizes, int n_in,
                              void* d_out, int out_size, void* d_ws, size_t ws_size,
                              hipStream_t stream) {
    const float* x    = (const float*)d_in[0];
    const int*   ei   = (const int*)d_in[1];
    const float* W1l  = (const float*)d_in[2];
    const float* W1r  = (const float*)d_in[3];
    const float* att1 = (const float*)d_in[4];
    const float* b1   = (const float*)d_in[5];
    const float* W2l  = (const float*)d_in[6];
    const float* W2r  = (const float*)d_in[7];
    const float* att2 = (const float*)d_in[8];
    const float* b2   = (const float*)d_in[9];
    const float* Wc   = (const float*)d_in[10];
    const float* bc   = (const float*)d_in[11];
    float* out = (float*)d_out;

    const int* srcIdx = ei;
    const int* dstIdx = ei + EE;

    constexpr int NB = (NN + 1023) / 1024;   // 49 scan blocks

    // workspace carve — total ≈ 166 MB
    bf16* XLR  = (bf16*)d_ws;                    // NN*D2   (XL || XR)
    bf16* Hb   = XLR + (size_t)NN * D2;          // NN*D
    bf16* Xpad = Hb + (size_t)NN * D;            // NN*F0P
    bf16* W2T  = Xpad + (size_t)NN * F0P;        // 1024*D   (W2lT || W2rT rows)
    bf16* W1T  = W2T + (size_t)D2 * D;           // 1024*F0P
    bf16* WcT  = W1T + (size_t)D2 * F0P;         // 128*D
    int* cnt   = (int*)(WcT + (size_t)128 * D);  // NN
    int* cnt2  = cnt + NN;                       // NN
    int* off   = cnt2 + NN;                      // NN+1
    int* srcPos= off + (NN + 1);                 // EP
    int* bsum  = srcPos + EP;                    // NB
    int* bbase = bsum + NB;                      // NB

    // ---- one-time per call: CSR build + weight prep ----
    zero_ints<<<(2 * NN + 255) / 256, 256, 0, stream>>>(cnt, 2 * NN);
    count_dst<<<(EP + 255) / 256, 256, 0, stream>>>(dstIdx, cnt);
    scan_blocks<<<NB, 1024, 0, stream>>>(cnt, off, bsum);
    scan_bsums<<<1, 64, 0, stream>>>(bsum, bbase, off, NB);
    add_base<<<NB, 1024, 0, stream>>>(off, bbase);
    fill_srcpos<<<(EP + 255) / 256, 256, 0, stream>>>(srcIdx, dstIdx, off, cnt2, srcPos);

    dim3 ctGrid(D / 32, D / 32, 2);
    convert_transpose2<<<ctGrid, 256, 0, stream>>>(W2l, W2r, W2T);
    dim3 w1Grid(D, 2);
    conv_transpose_w1<<<w1Grid, F0P, 0, stream>>>(W1l, W1r, W1T);
    conv_transpose_wc<<<128, 256, 0, stream>>>(Wc, WcT);
    pad_convert_x<<<(NN * F0P + 255) / 256, 256, 0, stream>>>(x, Xpad);

    // BM=256 row-panels: pad grid.y to a multiple of 8 for the XCD swizzle
    int panels = (NN + 255) / 256;                       // 196
    int gy = (panels + 7) / 8 * 8;                       // 200
    dim3 gemmGrid(D2 / 128, gy);                         // 8 x 200
    int nodeBlocks = (NN + 3) / 4;

    // ---- layer 1 (Xpad bf16, K=64): one GEMM produces XL||XR ----
    gemm_dp<bf16, 2><<<gemmGrid, 512, 0, stream>>>(Xpad, W1T, XLR, nullptr, NN, D2);
    gat_edge_fused<<<nodeBlocks, 256, 0, stream>>>(XLR, att1, off, srcPos, b1, Hb);

    // ---- layers 2 & 3 (bf16 Hb, K=512; conv2 applied twice) ----
    for (int rep = 0; rep < 2; ++rep) {
        gemm_dp<bf16, 16><<<gemmGrid, 512, 0, stream>>>(Hb, W2T, XLR, nullptr, NN, D2);
        gat_edge_fused<<<nodeBlocks, 256, 0, stream>>>(XLR, att2, off, srcPos, b2, Hb);
    }

    // ---- classifier: C[NN,49] fp32 = Hb @ Wc + bc (N padded to 128) ----
    dim3 gridc(1, panels);
    gemm_dp<float, 16><<<gridc, 512, 0, stream>>>(Hb, WcT, out, bc, NN, OUTC);
}